// Round 10
// baseline (587.120 us; speedup 1.0000x reference)
//
#include <hip/hip_runtime.h>
#include <math.h>

// ---------------- problem constants ----------------
constexpr int kN = 24000;     // nodes
constexpr int kE = 384000;    // edges
constexpr float kAlpha = 0.05f;

typedef unsigned int   u32;
typedef unsigned short u16;
typedef __attribute__((ext_vector_type(8))) short short8;
typedef __attribute__((ext_vector_type(4))) float float4v;

__device__ __forceinline__ float bf2f(u16 x) { return __uint_as_float(((u32)x) << 16); }
__device__ __forceinline__ u16 f2bf(float f) {
  u32 u = __float_as_uint(f);
  return (u16)((u + 0x7fffu + ((u >> 16) & 1u)) >> 16);
}

// ============================================================
// CSR build (segment-allocation variant; no global scan)
// ============================================================
__global__ void __launch_bounds__(256) zero_ints_kernel(int* __restrict__ p, int n) {
  int i = blockIdx.x * 256 + threadIdx.x;
  if (i < n) p[i] = 0;
}

__global__ void __launch_bounds__(256) count_kernel(const int* __restrict__ dst,
                                                    int* __restrict__ counts) {
  int e = blockIdx.x * 256 + threadIdx.x;
  if (e < kE) atomicAdd(&counts[dst[e]], 1);
}

// per-node segment start via wave prefix-scan + 1 atomic per wave
__global__ void __launch_bounds__(256) alloc_kernel(const int* __restrict__ counts,
                                                    int* __restrict__ gcur,
                                                    int* __restrict__ row_start) {
  int t = blockIdx.x * 256 + threadIdx.x;
  int lane = threadIdx.x & 63;
  int c = (t < kN) ? counts[t] : 0;
  int x = c;
  #pragma unroll
  for (int off = 1; off < 64; off <<= 1) {
    int y = __shfl_up(x, off);
    if (lane >= off) x += y;
  }
  int wtotal = __shfl(x, 63);
  int base = 0;
  if (lane == 63) base = atomicAdd(gcur, wtotal);
  base = __shfl(base, 63);
  if (t < kN) row_start[t] = base + x - c;
}

__global__ void __launch_bounds__(256) scatter_kernel(const int* __restrict__ dst,
                                                      const int* __restrict__ row_start,
                                                      int* __restrict__ cursor,
                                                      int* __restrict__ edge_ids) {
  int e = blockIdx.x * 256 + threadIdx.x;
  if (e < kE) {
    int n = dst[e];
    int pos = row_start[n] + atomicAdd(&cursor[n], 1);
    edge_ids[pos] = e;
  }
}

// ============================================================
// Merged precompute + weight-pack.
// ============================================================
__global__ void __launch_bounds__(256) prepack_kernel(
    const float* __restrict__ W0, const float* __restrict__ al0, const float* __restrict__ ar0,
    const float* __restrict__ W1, const float* __restrict__ al1, const float* __restrict__ ar1,
    const float* __restrict__ rW1,
    const float* __restrict__ W2, const float* __restrict__ al2, const float* __restrict__ ar2,
    const float* __restrict__ rW2,
    u16* __restrict__ WT0, u16* __restrict__ WT1, u16* __restrict__ WT2,
    const float* __restrict__ ntype_emb, const float* __restrict__ W_ntype,
    const float* __restrict__ emb0, const float* __restrict__ We0, const float* __restrict__ ae0,
    const float* __restrict__ emb1, const float* __restrict__ We1, const float* __restrict__ ae1,
    const float* __restrict__ emb2, const float* __restrict__ We2, const float* __restrict__ ae2,
    const float* __restrict__ ln1_b, const float* __restrict__ Wv, const float* __restrict__ bv,
    const float* __restrict__ Wo, const float* __restrict__ bo,
    const float* __restrict__ ln2_b, const float* __restrict__ DW1, const float* __restrict__ Db1,
    const float* __restrict__ DW2, const float* __restrict__ Db2,
    float* __restrict__ ntf, float* __restrict__ eterm, float* __restrict__ dadelta) {
  __shared__ float wae[17][64];
  __shared__ float red[128];
  int tid = threadIdx.x;
  if (blockIdx.x < 744) {
    const int SZ0 = 10240, SZ1 = 576 * 256;
    int gid = blockIdx.x * 256 + tid;
    float v = 0.f;
    if (gid < 2048) {                    // WT0el
      int n = gid / 32, k = gid % 32;
      if (n < 8)       { for (int d = 0; d < 32; ++d) v += W0[k * 256 + n * 32 + d] * al0[n * 32 + d]; }
      else if (n < 16) { int h = n - 8; for (int d = 0; d < 32; ++d) v += W0[k * 256 + h * 32 + d] * ar0[h * 32 + d]; }
      WT0[n * 32 + k] = f2bf(v);
    } else if (gid < SZ0) {              // Wbd0T
      int i = gid - 2048;
      int h = i >> 10, rem = i & 1023, d = rem >> 5, k = rem & 31;
      WT0[2048 + i] = f2bf(W0[k * 256 + h * 32 + d]);
    } else if (gid < SZ0 + SZ1) {
      int i = gid - SZ0;
      int n = i / 256, k = i % 256;
      if (n < 256) v = W1[k * 256 + n];
      else if (n < 264) { int h = n - 256; for (int d = 0; d < 32; ++d) v += W1[k * 256 + h * 32 + d] * al1[h * 32 + d]; }
      else if (n < 272) { int h = n - 264; for (int d = 0; d < 32; ++d) v += W1[k * 256 + h * 32 + d] * ar1[h * 32 + d]; }
      else if (n < 528) v = rW1[k * 256 + (n - 272)];
      WT1[n * 256 + k] = f2bf(v);
    } else {
      int i = gid - SZ0 - SZ1;
      int n = i / 256, k = i % 256;
      if (n < 32) v = W2[k * 32 + n];
      else if (n == 32) { for (int d = 0; d < 32; ++d) v += W2[k * 32 + d] * al2[d]; }
      else if (n == 33) { for (int d = 0; d < 32; ++d) v += W2[k * 32 + d] * ar2[d]; }
      else if (n < 66) v = rW2[k * 32 + (n - 34)];
      WT2[n * 256 + k] = f2bf(v);
    }
  } else {
    for (int idx = tid; idx < 17 * 64; idx += 256) {
      int hg = idx >> 6, k = idx & 63;
      const float* We; const float* ae; int Hh, h;
      if (hg < 8)       { We = We0; ae = ae0; Hh = 8; h = hg; }
      else if (hg < 16) { We = We1; ae = ae1; Hh = 8; h = hg - 8; }
      else              { We = We2; ae = ae2; Hh = 1; h = 0; }
      float s = 0.f;
      for (int d = 0; d < 64; ++d) s += We[(size_t)k * Hh * 64 + h * 64 + d] * ae[h * 64 + d];
      wae[hg][k] = s;
    }
    __syncthreads();
    for (int id = tid; id < 85; id += 256) {
      const float* emb; int Hh, t, h, hg, base;
      if (id < 40)      { emb = emb0; Hh = 8; t = id / 8;  h = id % 8; hg = h;      base = 0;  }
      else if (id < 80) { int i = id - 40; emb = emb1; Hh = 8; t = i / 8; h = i % 8; hg = 8 + h; base = 40; }
      else              { int i = id - 80; emb = emb2; Hh = 1; t = i;    h = 0;     hg = 16;    base = 80; }
      float s = 0.f;
      for (int k = 0; k < 64; ++k) s += emb[t * 64 + k] * wae[hg][k];
      eterm[base + t * Hh + h] = s;
    }
    for (int idx = tid; idx < 96; idx += 256) {
      int t = idx / 32, o = idx % 32;
      float s = 0.f;
      for (int k = 0; k < 32; ++k) s += ntype_emb[t * 32 + k] * W_ntype[k * 32 + o];
      ntf[idx] = s;
    }
    for (int i2 = tid; i2 < 128; i2 += 256) {
      int l = i2 >> 6, j = i2 & 63;
      float u = ln2_b[l] * DW1[l * 64 + j] + Db1[l * 64 + j];
      float g = 0.5f * u * (1.0f + erff(u * 0.7071067811865476f));
      red[i2] = g * DW2[l * 64 + j];
    }
    __syncthreads();
    if (tid == 0) {
      float delta = 0.f;
      for (int l = 0; l < 2; ++l) {
        float vs = ln1_b[l] * Wv[l] + bv[l];
        delta += vs * Wo[l] + bo[l] + Db2[l];
      }
      for (int i = 0; i < 128; ++i) delta += red[i];
      *dadelta = delta;
    }
  }
}

// ============================================================
// Input projection -> Hb bf16
// ============================================================
__global__ void __launch_bounds__(256) inproj_kernel(
    const float* __restrict__ feats, const float* __restrict__ fc_W,
    const float* __restrict__ fc_b, const float* __restrict__ ntf,
    const int* __restrict__ node_type, u16* __restrict__ hb) {
  int t = blockIdx.x * 256 + threadIdx.x;
  if (t >= kN * 32) return;
  int n = t >> 5, o = t & 31;
  int ty = n / 8000;
  const float* fr = &feats[(size_t)n * 128];
  const float* w  = &fc_W[(size_t)ty * 4096 + o];
  float s = fc_b[ty * 32 + o];
  #pragma unroll
  for (int k = 0; k < 128; k += 4) {
    float4 f = *(const float4*)&fr[k];
    s += f.x * w[(k + 0) * 32] + f.y * w[(k + 1) * 32]
       + f.z * w[(k + 2) * 32] + f.w * w[(k + 3) * 32];
  }
  s = (s < 0.f) ? 0.01f * s : s;
  hb[t] = f2bf(s * ntf[node_type[n] * 32 + o]);
}

// ============================================================
// bf16 MFMA GEMM: block stages A once, handles tpb column tiles.
// SLAB=true: head-slab outputs (feat [8][N][32], el/er [8][N]).
// ============================================================
template <int K, bool SLAB>
__global__ void __launch_bounds__(256) mfma_gemm_kernel(
    const u16* __restrict__ A, const u16* __restrict__ WT,
    const float* __restrict__ bias,
    u16* __restrict__ featb, float* __restrict__ el, float* __restrict__ er,
    u16* __restrict__ resb, float* __restrict__ resf,
    int tpb, int N1, int HH, int N2) {
  constexpr int RB = K * 2;
  constexpr int CPR = K / 8;
  __shared__ __align__(16) u16 As[64 * K];
  __shared__ __align__(16) u16 Bs[64 * K];
  const int tid = threadIdx.x;
  const int l = tid & 63;
  const int w = tid >> 6;
  const int wm = w >> 1, wn = w & 1;
  const int m0 = blockIdx.y * 64;
  const int kslot = l >> 4;
  const int l15 = l & 15;

  #pragma unroll
  for (int c = tid; c < 64 * CPR; c += 256) {
    int row = c / CPR, ch = c - row * CPR;
    int off = (row * RB + ch * 16) ^ ((row & 7) << 4);
    *(uint4*)((char*)As + off) = *(const uint4*)(A + (size_t)(m0 + row) * K + ch * 8);
  }

  for (int t = 0; t < tpb; ++t) {
    int ct = blockIdx.x * tpb + t;
    __syncthreads();
    #pragma unroll
    for (int c = tid; c < 64 * CPR; c += 256) {
      int row = c / CPR, ch = c - row * CPR;
      int off = (row * RB + ch * 16) ^ ((row & 7) << 4);
      *(uint4*)((char*)Bs + off) = *(const uint4*)(WT + (size_t)(ct * 64 + row) * K + ch * 8);
    }
    __syncthreads();

    float4v acc[2][2];
    #pragma unroll
    for (int f = 0; f < 2; ++f)
      #pragma unroll
      for (int g = 0; g < 2; ++g) { acc[f][g][0]=0.f; acc[f][g][1]=0.f; acc[f][g][2]=0.f; acc[f][g][3]=0.f; }

    #pragma unroll
    for (int kc = 0; kc < K; kc += 32) {
      short8 af[2], bf[2];
      #pragma unroll
      for (int f = 0; f < 2; ++f) {
        int row = wm * 32 + f * 16 + l15;
        int off = (row * RB + kc * 2 + kslot * 16) ^ ((row & 7) << 4);
        af[f] = *(const short8*)((const char*)As + off);
      }
      #pragma unroll
      for (int g = 0; g < 2; ++g) {
        int n = wn * 32 + g * 16 + l15;
        int off = (n * RB + kc * 2 + kslot * 16) ^ ((n & 7) << 4);
        bf[g] = *(const short8*)((const char*)Bs + off);
      }
      #pragma unroll
      for (int f = 0; f < 2; ++f)
        #pragma unroll
        for (int g = 0; g < 2; ++g)
          acc[f][g] = __builtin_amdgcn_mfma_f32_16x16x32_bf16(af[f], bf[g], acc[f][g], 0, 0, 0);
    }

    const int rbase = kslot * 4;
    #pragma unroll
    for (int f = 0; f < 2; ++f) {
      #pragma unroll
      for (int g = 0; g < 2; ++g) {
        int gc = ct * 64 + wn * 32 + g * 16 + l15;
        #pragma unroll
        for (int reg = 0; reg < 4; ++reg) {
          int gr = m0 + wm * 32 + f * 16 + rbase + reg;
          float v = acc[f][g][reg];
          if (gc < N1) {
            if (SLAB) featb[((size_t)(gc >> 5) * kN + gr) * 32 + (gc & 31)] = f2bf(v);
            else      featb[(size_t)gr * N1 + gc] = f2bf(v);
          } else if (gc < N1 + HH) {
            if (SLAB) el[(size_t)(gc - N1) * kN + gr] = v;
            else      el[(size_t)gr * HH + (gc - N1)] = v;
          } else if (gc < N1 + 2 * HH) {
            if (SLAB) er[(size_t)(gc - N1 - HH) * kN + gr] = v;
            else      er[(size_t)gr * HH + (gc - N1 - HH)] = v;
          } else if (gc < N1 + 2 * HH + N2) {
            int c2 = gc - N1 - 2 * HH;
            float vv = v + bias[c2];
            if (resb) resb[(size_t)gr * N2 + c2] = f2bf(vv);
            else      resf[(size_t)gr * N2 + c2] = vv;
          }
        }
      }
    }
  }
}

// ============================================================
// L0 h-space aggregation: ONE wave per node, lane = h*8+s.
// a0 written to head slab [8][E].
// ============================================================
__global__ void __launch_bounds__(256) agg8h_kernel(
    const int* __restrict__ row_start, const int* __restrict__ counts,
    const int* __restrict__ edge_ids,
    const int* __restrict__ src, const int* __restrict__ ef,
    const float* __restrict__ el, const float* __restrict__ er,   // [N][8]
    const float* __restrict__ eterm,        // [NE][8]
    const u16* __restrict__ Hb,             // [N][32]
    _Float16* __restrict__ a0s,             // [8][E]
    u16* __restrict__ Gb) {                 // [N][256] (h,k)
  int n = (blockIdx.x * 256 + threadIdx.x) >> 6;
  if (n >= kN) return;
  int l = threadIdx.x & 63;
  int h = l >> 3, s = l & 7;
  int s0 = row_start[n], s1 = s0 + counts[n];
  float ern = er[n * 8 + h];
  float et0 = eterm[0 * 8 + h], et1 = eterm[1 * 8 + h], et2 = eterm[2 * 8 + h];
  float et3 = eterm[3 * 8 + h], et4 = eterm[4 * 8 + h];
  float m = -1e30f, ssum = 0.f;
  for (int i = s0 + s; i < s1; i += 8) {
    int e = edge_ids[i];
    int efc = ef[e];
    float etv = (efc == 0) ? et0 : (efc == 1) ? et1 : (efc == 2) ? et2 : (efc == 3) ? et3 : et4;
    float lg = el[src[e] * 8 + h] + ern + etv;
    lg = (lg < 0.f) ? 0.2f * lg : lg;
    if (lg > m) { ssum = ssum * expf(m - lg) + 1.f; m = lg; }
    else        { ssum += expf(lg - m); }
  }
  #pragma unroll
  for (int mk = 1; mk <= 4; mk <<= 1) {
    float om = __shfl_xor(m, mk);
    float os = __shfl_xor(ssum, mk);
    float nm = fmaxf(m, om);
    ssum = ssum * expf(m - nm) + os * expf(om - nm);
    m = nm;
  }
  float inv = 1.f / ssum;
  float4 acc = make_float4(0.f, 0.f, 0.f, 0.f);
  int i = s0;
  for (; i + 8 <= s1; i += 8) {
    int e = edge_ids[i + s];
    int sek = src[e];
    int efc = ef[e];
    float etv = (efc == 0) ? et0 : (efc == 1) ? et1 : (efc == 2) ? et2 : (efc == 3) ? et3 : et4;
    float lg = el[sek * 8 + h] + ern + etv;
    lg = (lg < 0.f) ? 0.2f * lg : lg;
    float am = expf(lg - m) * inv;
    a0s[(size_t)h * kE + e] = (_Float16)am;
    #pragma unroll
    for (int j = 0; j < 8; ++j) {
      float aj = __shfl(am, (h << 3) + j);
      int sej = __shfl(sek, j);
      ushort4 fv = *(const ushort4*)(Hb + (size_t)sej * 32 + s * 4);
      acc.x = fmaf(aj, bf2f(fv.x), acc.x);
      acc.y = fmaf(aj, bf2f(fv.y), acc.y);
      acc.z = fmaf(aj, bf2f(fv.z), acc.z);
      acc.w = fmaf(aj, bf2f(fv.w), acc.w);
    }
  }
  if (i < s1) {
    int cnt = s1 - i;
    float am = 0.f; int sek = 0;
    if (s < cnt) {
      int e = edge_ids[i + s];
      sek = src[e];
      int efc = ef[e];
      float etv = (efc == 0) ? et0 : (efc == 1) ? et1 : (efc == 2) ? et2 : (efc == 3) ? et3 : et4;
      float lg = el[sek * 8 + h] + ern + etv;
      lg = (lg < 0.f) ? 0.2f * lg : lg;
      am = expf(lg - m) * inv;
      a0s[(size_t)h * kE + e] = (_Float16)am;
    }
    for (int j = 0; j < cnt; ++j) {
      float aj = __shfl(am, (h << 3) + j);
      int sej = __shfl(sek, j);
      ushort4 fv = *(const ushort4*)(Hb + (size_t)sej * 32 + s * 4);
      acc.x = fmaf(aj, bf2f(fv.x), acc.x);
      acc.y = fmaf(aj, bf2f(fv.y), acc.y);
      acc.z = fmaf(aj, bf2f(fv.z), acc.z);
      acc.w = fmaf(aj, bf2f(fv.w), acc.w);
    }
  }
  ushort4 pw;
  pw.x = f2bf(acc.x); pw.y = f2bf(acc.y); pw.z = f2bf(acc.z); pw.w = f2bf(acc.w);
  *(ushort4*)(Gb + (size_t)n * 256 + h * 32 + s * 4) = pw;
}

// ============================================================
// Block-diagonal head GEMM (L0): rst0 = Gb @ blockdiag(W0) + bias, ELU.
// ============================================================
__global__ void __launch_bounds__(256) bd_gemm_kernel(
    const u16* __restrict__ Gb, const u16* __restrict__ WbdT,
    const float* __restrict__ bias, u16* __restrict__ outb) {
  __shared__ __align__(16) u16 As[64 * 256];
  __shared__ __align__(16) u16 Bs[8 * 32 * 32];
  const int tid = threadIdx.x;
  const int l = tid & 63;
  const int w = tid >> 6;
  const int m0 = blockIdx.x * 64;
  const int kslot = l >> 4, l15 = l & 15;
  for (int c = tid; c < 64 * 32; c += 256) {
    int row = c >> 5, ch = c & 31;
    int off = (row * 512 + ch * 16) ^ ((row & 7) << 4);
    *(uint4*)((char*)As + off) = *(const uint4*)(Gb + (size_t)(m0 + row) * 256 + ch * 8);
  }
  for (int c = tid; c < 256 * 4; c += 256) {
    int r = c >> 2, ch = c & 3;
    int off = (r * 64 + ch * 16) ^ ((r & 7) << 4);
    *(uint4*)((char*)Bs + off) = *(const uint4*)(WbdT + (size_t)r * 32 + ch * 8);
  }
  __syncthreads();
  #pragma unroll
  for (int hh = 0; hh < 2; ++hh) {
    int h = w * 2 + hh;
    short8 af[4];
    #pragma unroll
    for (int f = 0; f < 4; ++f) {
      int row = f * 16 + l15;
      int off = (row * 512 + h * 64 + kslot * 16) ^ ((row & 7) << 4);
      af[f] = *(const short8*)((const char*)As + off);
    }
    short8 bf[2];
    #pragma unroll
    for (int g = 0; g < 2; ++g) {
      int r = h * 32 + g * 16 + l15;
      int off = (r * 64 + kslot * 16) ^ ((r & 7) << 4);
      bf[g] = *(const short8*)((const char*)Bs + off);
    }
    #pragma unroll
    for (int f = 0; f < 4; ++f) {
      #pragma unroll
      for (int g = 0; g < 2; ++g) {
        float4v acc = {0.f, 0.f, 0.f, 0.f};
        acc = __builtin_amdgcn_mfma_f32_16x16x32_bf16(af[f], bf[g], acc, 0, 0, 0);
        #pragma unroll
        for (int reg = 0; reg < 4; ++reg) {
          int gr = m0 + f * 16 + kslot * 4 + reg;
          int gc = h * 32 + g * 16 + l15;
          float v = acc[reg] + bias[gc];
          v = (v > 0.f) ? v : expm1f(v);
          outb[(size_t)gr * 256 + gc] = f2bf(v);
        }
      }
    }
  }
}

// ============================================================
// L1 aggregation, XCD-pinned head slabs: hd = blockIdx.x & 7.
// Block = 32 slots x 8 lanes; lane owns 4 dims of head hd.
// feat slab [8][N][32] is ~1.5MB -> L2-resident per XCD.
// ============================================================
__global__ void __launch_bounds__(256) agg8s_kernel(
    const int* __restrict__ row_start, const int* __restrict__ counts,
    const int* __restrict__ edge_ids,
    const int* __restrict__ src, const int* __restrict__ ef,
    const float* __restrict__ el_s,         // [8][N]
    const float* __restrict__ er_s,         // [8][N]
    const float* __restrict__ eterm,        // [NE][8]
    const u16* __restrict__ feat_s,         // [8][N][32]
    const _Float16* __restrict__ a0s,       // [8][E]
    const u16* __restrict__ accb,           // [N][256]
    u16* __restrict__ outb) {               // [N][256]
  const int hd = blockIdx.x & 7;
  const int chunk = blockIdx.x >> 3;
  const int tid = threadIdx.x;
  const int slot = tid >> 3;            // 0..31
  const int g = tid & 7;                // lane within 8-lane node group
  const int n = chunk * 32 + slot;
  const int lbase = (tid & 63) & ~7;    // shfl base within wave
  int s0 = row_start[n], s1 = s0 + counts[n];
  const float* el_h = el_s + (size_t)hd * kN;
  const u16* feat_h = feat_s + (size_t)hd * kN * 32;
  const _Float16* a0_h = a0s + (size_t)hd * kE;
  float ern = er_s[(size_t)hd * kN + n];
  float et0 = eterm[0 * 8 + hd], et1 = eterm[1 * 8 + hd], et2 = eterm[2 * 8 + hd];
  float et3 = eterm[3 * 8 + hd], et4 = eterm[4 * 8 + hd];
  // pass 1
  float m = -1e30f, ssum = 0.f;
  for (int i = s0 + g; i < s1; i += 8) {
    int e = edge_ids[i];
    int efc = ef[e];
    float etv = (efc == 0) ? et0 : (efc == 1) ? et1 : (efc == 2) ? et2 : (efc == 3) ? et3 : et4;
    float lg = el_h[src[e]] + ern + etv;
    lg = (lg < 0.f) ? 0.2f * lg : lg;
    if (lg > m) { ssum = ssum * expf(m - lg) + 1.f; m = lg; }
    else        { ssum += expf(lg - m); }
  }
  #pragma unroll
  for (int mk = 1; mk <= 4; mk <<= 1) {
    float om = __shfl_xor(m, mk);
    float os = __shfl_xor(ssum, mk);
    float nm = fmaxf(m, om);
    ssum = ssum * expf(m - nm) + os * expf(om - nm);
    m = nm;
  }
  float inv = 1.f / ssum;
  // acc init from res (8B per lane)
  const size_t rowoff = (size_t)n * 256 + hd * 32 + g * 4;
  ushort4 rv = *(const ushort4*)(accb + rowoff);
  float4 acc = make_float4(bf2f(rv.x), bf2f(rv.y), bf2f(rv.z), bf2f(rv.w));
  // pass 2: chunks of 8 edges, dedup'd exp, blend a0
  int i = s0;
  for (; i + 8 <= s1; i += 8) {
    int e = edge_ids[i + g];
    int sek = src[e];
    int efc = ef[e];
    float etv = (efc == 0) ? et0 : (efc == 1) ? et1 : (efc == 2) ? et2 : (efc == 3) ? et3 : et4;
    float lg = el_h[sek] + ern + etv;
    lg = (lg < 0.f) ? 0.2f * lg : lg;
    float am = expf(lg - m) * inv;
    am = am * (1.f - kAlpha) + (float)a0_h[e] * kAlpha;
    #pragma unroll
    for (int j = 0; j < 8; ++j) {
      float aj = __shfl(am, lbase + j);
      int sej = __shfl(sek, lbase + j);
      ushort4 fv = *(const ushort4*)(feat_h + (size_t)sej * 32 + g * 4);
      acc.x = fmaf(aj, bf2f(fv.x), acc.x);
      acc.y = fmaf(aj, bf2f(fv.y), acc.y);
      acc.z = fmaf(aj, bf2f(fv.z), acc.z);
      acc.w = fmaf(aj, bf2f(fv.w), acc.w);
    }
  }
  if (i < s1) {
    int cnt = s1 - i;
    float am = 0.f; int sek = 0;
    if (g < cnt) {
      int e = edge_ids[i + g];
      sek = src[e];
      int efc = ef[e];
      float etv = (efc == 0) ? et0 : (efc == 1) ? et1 : (efc == 2) ? et2 : (efc == 3) ? et3 : et4;
      float lg = el_h[sek] + ern + etv;
      lg = (lg < 0.f) ? 0.2f * lg : lg;
      am = expf(lg - m) * inv;
      am = am * (1.f - kAlpha) + (float)a0_h[e] * kAlpha;
    }
    for (int j = 0; j < cnt; ++j) {
      float aj = __shfl(am, lbase + j);
      int sej = __shfl(sek, lbase + j);
      ushort4 fv = *(const ushort4*)(feat_h + (size_t)sej * 32 + g * 4);
      acc.x = fmaf(aj, bf2f(fv.x), acc.x);
      acc.y = fmaf(aj, bf2f(fv.y), acc.y);
      acc.z = fmaf(aj, bf2f(fv.z), acc.z);
      acc.w = fmaf(aj, bf2f(fv.w), acc.w);
    }
  }
  acc.x = (acc.x > 0.f) ? acc.x : expm1f(acc.x);
  acc.y = (acc.y > 0.f) ? acc.y : expm1f(acc.y);
  acc.z = (acc.z > 0.f) ? acc.z : expm1f(acc.z);
  acc.w = (acc.w > 0.f) ? acc.w : expm1f(acc.w);
  ushort4 pw;
  pw.x = f2bf(acc.x); pw.y = f2bf(acc.y); pw.z = f2bf(acc.z); pw.w = f2bf(acc.w);
  *(ushort4*)(outb + rowoff) = pw;
}

// ============================================================
// Fused L2 aggregation + final head: 32 lanes per node.
// ============================================================
__global__ void __launch_bounds__(256) aggw1_final_kernel(
    const int* __restrict__ row_start, const int* __restrict__ counts,
    const int* __restrict__ edge_ids,
    const int* __restrict__ src, const int* __restrict__ ef,
    const float* __restrict__ el, const float* __restrict__ er,
    const float* __restrict__ eterm,        // [NE]
    const u16* __restrict__ featb,          // [N][32]
    const float* __restrict__ S2,           // [N][32]
    const float* __restrict__ ntf, const int* __restrict__ node_type,
    const float* __restrict__ dadelta,
    const float* __restrict__ finalW, const float* __restrict__ logitsW,
    float* __restrict__ out) {
  __shared__ float fWs[2048];
  __shared__ float lWs[512];
  __shared__ float abuf[8][32];
  __shared__ float bbuf[8][32];
  __shared__ float sbuf[8][32];
  const int tid = threadIdx.x;
  for (int i = tid; i < 2048; i += 256) fWs[i] = finalW[i];
  for (int i = tid; i < 512; i += 256) lWs[i] = logitsW[i];
  const int slot = tid >> 5;
  const int g = tid & 31;
  const int gb = tid & 32;
  const int n = blockIdx.x * 8 + slot;
  const int s0 = row_start[n], s1 = s0 + counts[n];
  float ern = er[n];
  float et0 = eterm[0], et1 = eterm[1], et2 = eterm[2], et3 = eterm[3], et4 = eterm[4];
  float m = -1e30f, ssum = 0.f;
  for (int i = s0 + g; i < s1; i += 32) {
    int e = edge_ids[i];
    int efc = ef[e];
    float etv = (efc == 0) ? et0 : (efc == 1) ? et1 : (efc == 2) ? et2 : (efc == 3) ? et3 : et4;
    float lg = el[src[e]] + ern + etv;
    lg = (lg < 0.f) ? 0.2f * lg : lg;
    if (lg > m) { ssum = ssum * expf(m - lg) + 1.f; m = lg; }
    else        { ssum += expf(lg - m); }
  }
  #pragma unroll
  for (int mk = 1; mk <= 16; mk <<= 1) {
    float om = __shfl_xor(m, mk);
    float os = __shfl_xor(ssum, mk);
    float nm = fmaxf(m, om);
    ssum = ssum * expf(m - nm) + os * expf(om - nm);
    m = nm;
  }
  float inv = 1.f / ssum;
  float acc = S2[(size_t)n * 32 + g];
  int i = s0;
  for (; i + 32 <= s1; i += 32) {
    int e = edge_ids[i + g];
    int sek = src[e];
    int efc = ef[e];
    float etv = (efc == 0) ? et0 : (efc == 1) ? et1 : (efc == 2) ? et2 : (efc == 3) ? et3 : et4;
    float lg = el[sek] + ern + etv;
    lg = (lg < 0.f) ? 0.2f * lg : lg;
    float am = expf(lg - m) * inv;
    #pragma unroll
    for (int j = 0; j < 32; ++j) {
      float aj = __shfl(am, gb + j);
      int sej = __shfl(sek, gb + j);
      acc = fmaf(aj, bf2f(featb[(size_t)sej * 32 + g]), acc);
    }
  }
  if (i < s1) {
    int cnt = s1 - i;
    float am = 0.f; int sek = 0;
    if (g < cnt) {
      int e = edge_ids[i + g];
      sek = src[e];
      int efc = ef[e];
      float etv = (efc == 0) ? et0 : (efc == 1) ? et1 : (efc == 2) ? et2 : (efc == 3) ? et3 : et4;
      float lg = el[sek] + ern + etv;
      lg = (lg < 0.f) ? 0.2f * lg : lg;
      am = expf(lg - m) * inv;
    }
    for (int j = 0; j < cnt; ++j) {
      float aj = __shfl(am, gb + j);
      int sej = __shfl(sek, gb + j);
      acc = fmaf(aj, bf2f(featb[(size_t)sej * 32 + g]), acc);
    }
  }
  float delta = dadelta[0];
  float ntv = ntf[node_type[n] * 32 + g];
  float av = acc;
  float bv = acc * ntv + delta;
  float na = av * av, nb = bv * bv;
  #pragma unroll
  for (int mk = 1; mk <= 16; mk <<= 1) {
    na += __shfl_xor(na, mk);
    nb += __shfl_xor(nb, mk);
  }
  float inva = 1.f / fmaxf(sqrtf(na), 1e-12f);
  float invb = 1.f / fmaxf(sqrtf(nb), 1e-12f);
  __syncthreads();
  abuf[slot][g] = av * inva;
  bbuf[slot][g] = bv * invb;
  __syncthreads();
  float s = 0.f;
  #pragma unroll
  for (int d = 0; d < 32; ++d)
    s += abuf[slot][d] * fWs[d * 32 + g] + bbuf[slot][d] * fWs[(32 + d) * 32 + g];
  s = fmaxf(s, 0.f);
  sbuf[slot][g] = s;
  __syncthreads();
  if (g < 16) {
    float lg = 0.f;
    #pragma unroll
    for (int o = 0; o < 32; ++o) lg += sbuf[slot][o] * lWs[o * 16 + g];
    float nl = lg * lg;
    #pragma unroll
    for (int mk = 1; mk <= 8; mk <<= 1) nl += __shfl_xor(nl, mk);
    float invl = 1.f / fmaxf(sqrtf(nl), 1e-12f);
    out[(size_t)n * 16 + g] = lg * invl;
  }
}

// ============================================================
extern "C" void kernel_launch(void* const* d_in, const int* in_sizes, int n_in,
                              void* d_out, int out_size, void* d_ws, size_t ws_size,
                              hipStream_t stream) {
  const float* feats     = (const float*)d_in[0];
  const int*   e_feat    = (const int*)d_in[1];
  const int*   node_type = (const int*)d_in[2];
  const int*   src       = (const int*)d_in[3];
  const int*   dst       = (const int*)d_in[4];
  const float* fc_W      = (const float*)d_in[5];
  const float* fc_b      = (const float*)d_in[6];
  const float* ntype_emb = (const float*)d_in[7];
  const float* W_ntype   = (const float*)d_in[8];
  const float* ta_edge_emb[3] = {(const float*)d_in[9],  (const float*)d_in[16], (const float*)d_in[24]};
  const float* ta_W[3]        = {(const float*)d_in[10], (const float*)d_in[17], (const float*)d_in[25]};
  const float* ta_We[3]       = {(const float*)d_in[11], (const float*)d_in[18], (const float*)d_in[26]};
  const float* ta_al[3]       = {(const float*)d_in[12], (const float*)d_in[19], (const float*)d_in[27]};
  const float* ta_ar[3]       = {(const float*)d_in[13], (const float*)d_in[20], (const float*)d_in[28]};
  const float* ta_ae[3]       = {(const float*)d_in[14], (const float*)d_in[21], (const float*)d_in[29]};
  const float* ta_bias[3]     = {(const float*)d_in[15], (const float*)d_in[22], (const float*)d_in[30]};
  const float* ta1_res_W = (const float*)d_in[23];
  const float* ta2_res_W = (const float*)d_in[31];
  const float* da_ln1_b  = (const float*)d_in[33];
  const float* da_Wv     = (const float*)d_in[38];
  const float* da_bv     = (const float*)d_in[39];
  const float* da_Wo     = (const float*)d_in[40];
  const float* da_bo     = (const float*)d_in[41];
  const float* da_ln2_b  = (const float*)d_in[43];
  const float* da_W1     = (const float*)d_in[44];
  const float* da_b1     = (const float*)d_in[45];
  const float* da_W2     = (const float*)d_in[46];
  const float* da_b2     = (const float*)d_in[47];
  const float* final_W   = (const float*)d_in[48];
  const float* logits_W  = (const float*)d_in[49];
  float* out = (float*)d_out;

  // ---- workspace layout (~51.3 MB, proven safe) ----
  char* base = (char*)d_ws;
  int* iws       = (int*)base;
  int* counts    = iws;                       // kN
  int* cursor    = iws + kN;                  // kN
  int* gcur      = iws + 2 * kN;              // 4 (padded)
  int* row_start = iws + 2 * kN + 4;          // kN
  int* edge_ids  = iws + 3 * kN + 4;          // kE
  char* p = base + (size_t)456004 * 4;
  float* ntf = (float*)p;                     p += 512;
  float* etm = (float*)p;                     p += 512;
  float* dad = (float*)p;                     p += 64;
  float* el  = (float*)p;                     p += (size_t)kN * 8 * 4;   // [N][8] or [8][N]
  float* er  = (float*)p;                     p += (size_t)kN * 8 * 4;
  float* S2  = (float*)p;                     p += (size_t)kN * 32 * 4;
  u16*   Hb  = (u16*)p;                       p += (size_t)kN * 32 * 2;
  _Float16* a0s = (_Float16*)p;               p += (size_t)kE * 8 * 2;   // [8][E]
  u16* featb = (u16*)p;                       p += (size_t)kN * 256 * 2; // Gb / [8][N][32] / [N][32]
  u16* Rb0   = (u16*)p;                       p += (size_t)kN * 256 * 2;
  u16* Rpr   = (u16*)p;                       p += (size_t)kN * 256 * 2;
  u16* WT0   = (u16*)p;                       p += (size_t)320 * 32 * 2;
  u16* WT1   = (u16*)p;                       p += (size_t)576 * 256 * 2;
  u16* WT2   = (u16*)p;                       p += (size_t)128 * 256 * 2;
  u16* WT0el = WT0;
  u16* Wbd0T = WT0 + 2048;

  // --- CSR build (no serial scan) ---
  zero_ints_kernel<<<(2 * kN + 4 + 255) / 256, 256, 0, stream>>>(counts, 2 * kN + 4);
  count_kernel<<<kE / 256, 256, 0, stream>>>(dst, counts);
  alloc_kernel<<<(kN + 255) / 256, 256, 0, stream>>>(counts, gcur, row_start);
  scatter_kernel<<<kE / 256, 256, 0, stream>>>(dst, row_start, cursor, edge_ids);

  // --- merged precompute + pack ---
  prepack_kernel<<<745, 256, 0, stream>>>(
      ta_W[0], ta_al[0], ta_ar[0],
      ta_W[1], ta_al[1], ta_ar[1], ta1_res_W,
      ta_W[2], ta_al[2], ta_ar[2], ta2_res_W,
      WT0, WT1, WT2,
      ntype_emb, W_ntype,
      ta_edge_emb[0], ta_We[0], ta_ae[0],
      ta_edge_emb[1], ta_We[1], ta_ae[1],
      ta_edge_emb[2], ta_We[2], ta_ae[2],
      da_ln1_b, da_Wv, da_bv, da_Wo, da_bo,
      da_ln2_b, da_W1, da_b1, da_W2, da_b2,
      ntf, etm, dad);

  // --- input projection -> Hb bf16 ---
  inproj_kernel<<<(kN * 32) / 256, 256, 0, stream>>>(feats, fc_W, fc_b, ntf, node_type, Hb);

  // --- TA layer 0: el/er GEMM ([N][8]); h-space agg -> Gb; per-head GEMM -> Rb0 ---
  mfma_gemm_kernel<32, false><<<dim3(1, kN / 64), 256, 0, stream>>>(
      Hb, WT0el, nullptr, nullptr, el, er, nullptr, nullptr, 1, 0, 8, 0);
  agg8h_kernel<<<kN / 4, 256, 0, stream>>>(
      row_start, counts, edge_ids, src, e_feat, el, er, etm, Hb, a0s, featb);
  bd_gemm_kernel<<<kN / 64, 256, 0, stream>>>(featb, Wbd0T, ta_bias[0], Rb0);

  // --- TA layer 1: fused GEMM (slab outputs) then XCD-pinned head agg ---
  mfma_gemm_kernel<256, true><<<dim3(3, kN / 64), 256, 0, stream>>>(
      Rb0, WT1, ta_bias[1], featb, el, er, Rpr, nullptr, 3, 256, 8, 256);
  agg8s_kernel<<<(kN / 32) * 8, 256, 0, stream>>>(
      row_start, counts, edge_ids, src, e_feat, el, er, etm + 40,
      featb, a0s, Rpr, Rpr);

  // --- TA layer 2: fused GEMM then fused 32-lane agg + final head ---
  mfma_gemm_kernel<256, false><<<dim3(2, kN / 64), 256, 0, stream>>>(
      Rpr, WT2, ta_bias[2], featb, el, er, nullptr, S2, 1, 32, 1, 32);
  aggw1_final_kernel<<<kN / 8, 256, 0, stream>>>(
      row_start, counts, edge_ids, src, e_feat, el, er, etm + 80, featb, S2,
      ntf, node_type, dad, final_W, logits_W, out);
}

// Round 11
// 483.743 us; speedup vs baseline: 1.2137x; 1.2137x over previous
//
#include <hip/hip_runtime.h>
#include <math.h>

// ---------------- problem constants ----------------
constexpr int kN = 24000;     // nodes
constexpr int kE = 384000;    // edges
constexpr float kAlpha = 0.05f;

typedef unsigned int   u32;
typedef unsigned short u16;
typedef __attribute__((ext_vector_type(8))) short short8;
typedef __attribute__((ext_vector_type(4))) float float4v;

__device__ __forceinline__ float bf2f(u16 x) { return __uint_as_float(((u32)x) << 16); }
__device__ __forceinline__ u16 f2bf(float f) {
  u32 u = __float_as_uint(f);
  return (u16)((u + 0x7fffu + ((u >> 16) & 1u)) >> 16);
}

// ============================================================
// CSR build (segment-allocation; no global scan)
// ============================================================
__global__ void __launch_bounds__(256) zero_ints_kernel(int* __restrict__ p, int n) {
  int i = blockIdx.x * 256 + threadIdx.x;
  if (i < n) p[i] = 0;
}

__global__ void __launch_bounds__(256) count_kernel(const int* __restrict__ dst,
                                                    int* __restrict__ counts) {
  int e = blockIdx.x * 256 + threadIdx.x;
  if (e < kE) atomicAdd(&counts[dst[e]], 1);
}

__global__ void __launch_bounds__(256) alloc_kernel(const int* __restrict__ counts,
                                                    int* __restrict__ gcur,
                                                    int* __restrict__ row_start) {
  int t = blockIdx.x * 256 + threadIdx.x;
  int lane = threadIdx.x & 63;
  int c = (t < kN) ? counts[t] : 0;
  int x = c;
  #pragma unroll
  for (int off = 1; off < 64; off <<= 1) {
    int y = __shfl_up(x, off);
    if (lane >= off) x += y;
  }
  int wtotal = __shfl(x, 63);
  int base = 0;
  if (lane == 63) base = atomicAdd(gcur, wtotal);
  base = __shfl(base, 63);
  if (t < kN) row_start[t] = base + x - c;
}

__global__ void __launch_bounds__(256) scatter_kernel(const int* __restrict__ dst,
                                                      const int* __restrict__ row_start,
                                                      int* __restrict__ cursor,
                                                      int* __restrict__ edge_ids) {
  int e = blockIdx.x * 256 + threadIdx.x;
  if (e < kE) {
    int n = dst[e];
    int pos = row_start[n] + atomicAdd(&cursor[n], 1);
    edge_ids[pos] = e;
  }
}

// ============================================================
// Merged precompute + weight-pack.
// WT0: [0,2048) WT0el (64 rows x 32K: rows 0..7 el, 8..15 er);
//      [2048,10240) Wbd0T [8][32][32] = W0[k][h*32+d].
// ============================================================
__global__ void __launch_bounds__(256) prepack_kernel(
    const float* __restrict__ W0, const float* __restrict__ al0, const float* __restrict__ ar0,
    const float* __restrict__ W1, const float* __restrict__ al1, const float* __restrict__ ar1,
    const float* __restrict__ rW1,
    const float* __restrict__ W2, const float* __restrict__ al2, const float* __restrict__ ar2,
    const float* __restrict__ rW2,
    u16* __restrict__ WT0, u16* __restrict__ WT1, u16* __restrict__ WT2,
    const float* __restrict__ ntype_emb, const float* __restrict__ W_ntype,
    const float* __restrict__ emb0, const float* __restrict__ We0, const float* __restrict__ ae0,
    const float* __restrict__ emb1, const float* __restrict__ We1, const float* __restrict__ ae1,
    const float* __restrict__ emb2, const float* __restrict__ We2, const float* __restrict__ ae2,
    const float* __restrict__ ln1_b, const float* __restrict__ Wv, const float* __restrict__ bv,
    const float* __restrict__ Wo, const float* __restrict__ bo,
    const float* __restrict__ ln2_b, const float* __restrict__ DW1, const float* __restrict__ Db1,
    const float* __restrict__ DW2, const float* __restrict__ Db2,
    float* __restrict__ ntf, float* __restrict__ eterm, float* __restrict__ dadelta) {
  __shared__ float wae[17][64];
  __shared__ float red[128];
  int tid = threadIdx.x;
  if (blockIdx.x < 744) {
    const int SZ0 = 10240, SZ1 = 576 * 256;
    int gid = blockIdx.x * 256 + tid;
    float v = 0.f;
    if (gid < 2048) {
      int n = gid / 32, k = gid % 32;
      if (n < 8)       { for (int d = 0; d < 32; ++d) v += W0[k * 256 + n * 32 + d] * al0[n * 32 + d]; }
      else if (n < 16) { int h = n - 8; for (int d = 0; d < 32; ++d) v += W0[k * 256 + h * 32 + d] * ar0[h * 32 + d]; }
      WT0[n * 32 + k] = f2bf(v);
    } else if (gid < SZ0) {
      int i = gid - 2048;
      int h = i >> 10, rem = i & 1023, d = rem >> 5, k = rem & 31;
      WT0[2048 + i] = f2bf(W0[k * 256 + h * 32 + d]);
    } else if (gid < SZ0 + SZ1) {
      int i = gid - SZ0;
      int n = i / 256, k = i % 256;
      if (n < 256) v = W1[k * 256 + n];
      else if (n < 264) { int h = n - 256; for (int d = 0; d < 32; ++d) v += W1[k * 256 + h * 32 + d] * al1[h * 32 + d]; }
      else if (n < 272) { int h = n - 264; for (int d = 0; d < 32; ++d) v += W1[k * 256 + h * 32 + d] * ar1[h * 32 + d]; }
      else if (n < 528) v = rW1[k * 256 + (n - 272)];
      WT1[n * 256 + k] = f2bf(v);
    } else {
      int i = gid - SZ0 - SZ1;
      int n = i / 256, k = i % 256;
      if (n < 32) v = W2[k * 32 + n];
      else if (n == 32) { for (int d = 0; d < 32; ++d) v += W2[k * 32 + d] * al2[d]; }
      else if (n == 33) { for (int d = 0; d < 32; ++d) v += W2[k * 32 + d] * ar2[d]; }
      else if (n < 66) v = rW2[k * 32 + (n - 34)];
      WT2[n * 256 + k] = f2bf(v);
    }
  } else {
    for (int idx = tid; idx < 17 * 64; idx += 256) {
      int hg = idx >> 6, k = idx & 63;
      const float* We; const float* ae; int Hh, h;
      if (hg < 8)       { We = We0; ae = ae0; Hh = 8; h = hg; }
      else if (hg < 16) { We = We1; ae = ae1; Hh = 8; h = hg - 8; }
      else              { We = We2; ae = ae2; Hh = 1; h = 0; }
      float s = 0.f;
      for (int d = 0; d < 64; ++d) s += We[(size_t)k * Hh * 64 + h * 64 + d] * ae[h * 64 + d];
      wae[hg][k] = s;
    }
    __syncthreads();
    for (int id = tid; id < 85; id += 256) {
      const float* emb; int Hh, t, h, hg, base;
      if (id < 40)      { emb = emb0; Hh = 8; t = id / 8;  h = id % 8; hg = h;      base = 0;  }
      else if (id < 80) { int i = id - 40; emb = emb1; Hh = 8; t = i / 8; h = i % 8; hg = 8 + h; base = 40; }
      else              { int i = id - 80; emb = emb2; Hh = 1; t = i;    h = 0;     hg = 16;    base = 80; }
      float s = 0.f;
      for (int k = 0; k < 64; ++k) s += emb[t * 64 + k] * wae[hg][k];
      eterm[base + t * Hh + h] = s;
    }
    for (int idx = tid; idx < 96; idx += 256) {
      int t = idx / 32, o = idx % 32;
      float s = 0.f;
      for (int k = 0; k < 32; ++k) s += ntype_emb[t * 32 + k] * W_ntype[k * 32 + o];
      ntf[idx] = s;
    }
    for (int i2 = tid; i2 < 128; i2 += 256) {
      int l = i2 >> 6, j = i2 & 63;
      float u = ln2_b[l] * DW1[l * 64 + j] + Db1[l * 64 + j];
      float g = 0.5f * u * (1.0f + erff(u * 0.7071067811865476f));
      red[i2] = g * DW2[l * 64 + j];
    }
    __syncthreads();
    if (tid == 0) {
      float delta = 0.f;
      for (int l = 0; l < 2; ++l) {
        float vs = ln1_b[l] * Wv[l] + bv[l];
        delta += vs * Wo[l] + bo[l] + Db2[l];
      }
      for (int i = 0; i < 128; ++i) delta += red[i];
      *dadelta = delta;
    }
  }
}

// ============================================================
// Input projection -> Hb bf16
// ============================================================
__global__ void __launch_bounds__(256) inproj_kernel(
    const float* __restrict__ feats, const float* __restrict__ fc_W,
    const float* __restrict__ fc_b, const float* __restrict__ ntf,
    const int* __restrict__ node_type, u16* __restrict__ hb) {
  int t = blockIdx.x * 256 + threadIdx.x;
  if (t >= kN * 32) return;
  int n = t >> 5, o = t & 31;
  int ty = n / 8000;
  const float* fr = &feats[(size_t)n * 128];
  const float* w  = &fc_W[(size_t)ty * 4096 + o];
  float s = fc_b[ty * 32 + o];
  #pragma unroll
  for (int k = 0; k < 128; k += 4) {
    float4 f = *(const float4*)&fr[k];
    s += f.x * w[(k + 0) * 32] + f.y * w[(k + 1) * 32]
       + f.z * w[(k + 2) * 32] + f.w * w[(k + 3) * 32];
  }
  s = (s < 0.f) ? 0.01f * s : s;
  hb[t] = f2bf(s * ntf[node_type[n] * 32 + o]);
}

// ============================================================
// bf16 MFMA GEMM: block stages A once, handles tpb column tiles.
//   cols [0,N1) -> featb bf16 [M][N1]; [N1,N1+HH) -> el [M][HH];
//   [..+HH) -> er; [..,..+N2) -> res+bias -> resb bf16 / resf f32.
// ============================================================
template <int K>
__global__ void __launch_bounds__(256) mfma_gemm_kernel(
    const u16* __restrict__ A, const u16* __restrict__ WT,
    const float* __restrict__ bias,
    u16* __restrict__ featb, float* __restrict__ el, float* __restrict__ er,
    u16* __restrict__ resb, float* __restrict__ resf,
    int tpb, int N1, int HH, int N2) {
  constexpr int RB = K * 2;
  constexpr int CPR = K / 8;
  __shared__ __align__(16) u16 As[64 * K];
  __shared__ __align__(16) u16 Bs[64 * K];
  const int tid = threadIdx.x;
  const int l = tid & 63;
  const int w = tid >> 6;
  const int wm = w >> 1, wn = w & 1;
  const int m0 = blockIdx.y * 64;
  const int kslot = l >> 4;
  const int l15 = l & 15;

  #pragma unroll
  for (int c = tid; c < 64 * CPR; c += 256) {
    int row = c / CPR, ch = c - row * CPR;
    int off = (row * RB + ch * 16) ^ ((row & 7) << 4);
    *(uint4*)((char*)As + off) = *(const uint4*)(A + (size_t)(m0 + row) * K + ch * 8);
  }

  for (int t = 0; t < tpb; ++t) {
    int ct = blockIdx.x * tpb + t;
    __syncthreads();
    #pragma unroll
    for (int c = tid; c < 64 * CPR; c += 256) {
      int row = c / CPR, ch = c - row * CPR;
      int off = (row * RB + ch * 16) ^ ((row & 7) << 4);
      *(uint4*)((char*)Bs + off) = *(const uint4*)(WT + (size_t)(ct * 64 + row) * K + ch * 8);
    }
    __syncthreads();

    float4v acc[2][2];
    #pragma unroll
    for (int f = 0; f < 2; ++f)
      #pragma unroll
      for (int g = 0; g < 2; ++g) { acc[f][g][0]=0.f; acc[f][g][1]=0.f; acc[f][g][2]=0.f; acc[f][g][3]=0.f; }

    #pragma unroll
    for (int kc = 0; kc < K; kc += 32) {
      short8 af[2], bf[2];
      #pragma unroll
      for (int f = 0; f < 2; ++f) {
        int row = wm * 32 + f * 16 + l15;
        int off = (row * RB + kc * 2 + kslot * 16) ^ ((row & 7) << 4);
        af[f] = *(const short8*)((const char*)As + off);
      }
      #pragma unroll
      for (int g = 0; g < 2; ++g) {
        int n = wn * 32 + g * 16 + l15;
        int off = (n * RB + kc * 2 + kslot * 16) ^ ((n & 7) << 4);
        bf[g] = *(const short8*)((const char*)Bs + off);
      }
      #pragma unroll
      for (int f = 0; f < 2; ++f)
        #pragma unroll
        for (int g = 0; g < 2; ++g)
          acc[f][g] = __builtin_amdgcn_mfma_f32_16x16x32_bf16(af[f], bf[g], acc[f][g], 0, 0, 0);
    }

    const int rbase = kslot * 4;
    #pragma unroll
    for (int f = 0; f < 2; ++f) {
      #pragma unroll
      for (int g = 0; g < 2; ++g) {
        int gc = ct * 64 + wn * 32 + g * 16 + l15;
        #pragma unroll
        for (int reg = 0; reg < 4; ++reg) {
          int gr = m0 + wm * 32 + f * 16 + rbase + reg;
          float v = acc[f][g][reg];
          if (gc < N1) {
            featb[(size_t)gr * N1 + gc] = f2bf(v);
          } else if (gc < N1 + HH) {
            el[(size_t)gr * HH + (gc - N1)] = v;
          } else if (gc < N1 + 2 * HH) {
            er[(size_t)gr * HH + (gc - N1 - HH)] = v;
          } else if (gc < N1 + 2 * HH + N2) {
            int c2 = gc - N1 - 2 * HH;
            float vv = v + bias[c2];
            if (resb) resb[(size_t)gr * N2 + c2] = f2bf(vv);
            else      resf[(size_t)gr * N2 + c2] = vv;
          }
        }
      }
    }
  }
}

// ============================================================
// L0 h-space aggregation: ONE wave per node, lane = h*8+s.
// Gathers Hb rows (64 B/edge, broadcast across heads). Writes
// a0 interleaved [E][8]. Output Gb [N][256] (h,k).
// ============================================================
__global__ void __launch_bounds__(256) agg8h_kernel(
    const int* __restrict__ row_start, const int* __restrict__ counts,
    const int* __restrict__ edge_ids,
    const int* __restrict__ src, const int* __restrict__ ef,
    const float* __restrict__ el, const float* __restrict__ er,   // [N][8]
    const float* __restrict__ eterm,        // [NE][8]
    const u16* __restrict__ Hb,             // [N][32]
    _Float16* __restrict__ a0h,             // [E][8]
    u16* __restrict__ Gb) {                 // [N][256] (h,k)
  int n = (blockIdx.x * 256 + threadIdx.x) >> 6;
  if (n >= kN) return;
  int l = threadIdx.x & 63;
  int h = l >> 3, s = l & 7;
  int s0 = row_start[n], s1 = s0 + counts[n];
  float ern = er[n * 8 + h];
  float et0 = eterm[0 * 8 + h], et1 = eterm[1 * 8 + h], et2 = eterm[2 * 8 + h];
  float et3 = eterm[3 * 8 + h], et4 = eterm[4 * 8 + h];
  float m = -1e30f, ssum = 0.f;
  for (int i = s0 + s; i < s1; i += 8) {
    int e = edge_ids[i];
    int efc = ef[e];
    float etv = (efc == 0) ? et0 : (efc == 1) ? et1 : (efc == 2) ? et2 : (efc == 3) ? et3 : et4;
    float lg = el[src[e] * 8 + h] + ern + etv;
    lg = (lg < 0.f) ? 0.2f * lg : lg;
    if (lg > m) { ssum = ssum * expf(m - lg) + 1.f; m = lg; }
    else        { ssum += expf(lg - m); }
  }
  #pragma unroll
  for (int mk = 1; mk <= 4; mk <<= 1) {
    float om = __shfl_xor(m, mk);
    float os = __shfl_xor(ssum, mk);
    float nm = fmaxf(m, om);
    ssum = ssum * expf(m - nm) + os * expf(om - nm);
    m = nm;
  }
  float inv = 1.f / ssum;
  float4 acc = make_float4(0.f, 0.f, 0.f, 0.f);
  int i = s0;
  for (; i + 8 <= s1; i += 8) {
    int e = edge_ids[i + s];
    int sek = src[e];
    int efc = ef[e];
    float etv = (efc == 0) ? et0 : (efc == 1) ? et1 : (efc == 2) ? et2 : (efc == 3) ? et3 : et4;
    float lg = el[sek * 8 + h] + ern + etv;
    lg = (lg < 0.f) ? 0.2f * lg : lg;
    float am = expf(lg - m) * inv;
    a0h[(size_t)e * 8 + h] = (_Float16)am;
    #pragma unroll
    for (int j = 0; j < 8; ++j) {
      float aj = __shfl(am, (h << 3) + j);
      int sej = __shfl(sek, j);
      ushort4 fv = *(const ushort4*)(Hb + (size_t)sej * 32 + s * 4);
      acc.x = fmaf(aj, bf2f(fv.x), acc.x);
      acc.y = fmaf(aj, bf2f(fv.y), acc.y);
      acc.z = fmaf(aj, bf2f(fv.z), acc.z);
      acc.w = fmaf(aj, bf2f(fv.w), acc.w);
    }
  }
  if (i < s1) {
    int cnt = s1 - i;
    float am = 0.f; int sek = 0;
    if (s < cnt) {
      int e = edge_ids[i + s];
      sek = src[e];
      int efc = ef[e];
      float etv = (efc == 0) ? et0 : (efc == 1) ? et1 : (efc == 2) ? et2 : (efc == 3) ? et3 : et4;
      float lg = el[sek * 8 + h] + ern + etv;
      lg = (lg < 0.f) ? 0.2f * lg : lg;
      am = expf(lg - m) * inv;
      a0h[(size_t)e * 8 + h] = (_Float16)am;
    }
    for (int j = 0; j < cnt; ++j) {
      float aj = __shfl(am, (h << 3) + j);
      int sej = __shfl(sek, j);
      ushort4 fv = *(const ushort4*)(Hb + (size_t)sej * 32 + s * 4);
      acc.x = fmaf(aj, bf2f(fv.x), acc.x);
      acc.y = fmaf(aj, bf2f(fv.y), acc.y);
      acc.z = fmaf(aj, bf2f(fv.z), acc.z);
      acc.w = fmaf(aj, bf2f(fv.w), acc.w);
    }
  }
  ushort4 pw;
  pw.x = f2bf(acc.x); pw.y = f2bf(acc.y); pw.z = f2bf(acc.z); pw.w = f2bf(acc.w);
  *(ushort4*)(Gb + (size_t)n * 256 + h * 32 + s * 4) = pw;
}

// ============================================================
// Block-diagonal head GEMM (L0): rst0 = Gb @ blockdiag(W0) + bias, ELU.
// ============================================================
__global__ void __launch_bounds__(256) bd_gemm_kernel(
    const u16* __restrict__ Gb, const u16* __restrict__ WbdT,
    const float* __restrict__ bias, u16* __restrict__ outb) {
  __shared__ __align__(16) u16 As[64 * 256];
  __shared__ __align__(16) u16 Bs[8 * 32 * 32];
  const int tid = threadIdx.x;
  const int l = tid & 63;
  const int w = tid >> 6;
  const int m0 = blockIdx.x * 64;
  const int kslot = l >> 4, l15 = l & 15;
  for (int c = tid; c < 64 * 32; c += 256) {
    int row = c >> 5, ch = c & 31;
    int off = (row * 512 + ch * 16) ^ ((row & 7) << 4);
    *(uint4*)((char*)As + off) = *(const uint4*)(Gb + (size_t)(m0 + row) * 256 + ch * 8);
  }
  for (int c = tid; c < 256 * 4; c += 256) {
    int r = c >> 2, ch = c & 3;
    int off = (r * 64 + ch * 16) ^ ((r & 7) << 4);
    *(uint4*)((char*)Bs + off) = *(const uint4*)(WbdT + (size_t)r * 32 + ch * 8);
  }
  __syncthreads();
  #pragma unroll
  for (int hh = 0; hh < 2; ++hh) {
    int h = w * 2 + hh;
    short8 af[4];
    #pragma unroll
    for (int f = 0; f < 4; ++f) {
      int row = f * 16 + l15;
      int off = (row * 512 + h * 64 + kslot * 16) ^ ((row & 7) << 4);
      af[f] = *(const short8*)((const char*)As + off);
    }
    short8 bf[2];
    #pragma unroll
    for (int g = 0; g < 2; ++g) {
      int r = h * 32 + g * 16 + l15;
      int off = (r * 64 + kslot * 16) ^ ((r & 7) << 4);
      bf[g] = *(const short8*)((const char*)Bs + off);
    }
    #pragma unroll
    for (int f = 0; f < 4; ++f) {
      #pragma unroll
      for (int g = 0; g < 2; ++g) {
        float4v acc = {0.f, 0.f, 0.f, 0.f};
        acc = __builtin_amdgcn_mfma_f32_16x16x32_bf16(af[f], bf[g], acc, 0, 0, 0);
        #pragma unroll
        for (int reg = 0; reg < 4; ++reg) {
          int gr = m0 + f * 16 + kslot * 4 + reg;
          int gc = h * 32 + g * 16 + l15;
          float v = acc[reg] + bias[gc];
          v = (v > 0.f) ? v : expm1f(v);
          outb[(size_t)gr * 256 + gc] = f2bf(v);
        }
      }
    }
  }
}

// ============================================================
// L1 feat-space aggregation (HH=8): ONE wave per node.
// lane = h*8+s. Pass 2: 8-edge chunks, 1 exp per (edge,head),
// shfl broadcast; coalesced 512B featb reads; a0 blend.
// ============================================================
__global__ void __launch_bounds__(256) agg8w_kernel(
    const int* __restrict__ row_start, const int* __restrict__ counts,
    const int* __restrict__ edge_ids,
    const int* __restrict__ src, const int* __restrict__ ef,
    const float* __restrict__ el, const float* __restrict__ er,   // [N][8]
    const float* __restrict__ eterm,        // [NE][8]
    const u16* __restrict__ featb,          // [N][256] bf16
    const _Float16* __restrict__ a0h,       // [E][8]
    const u16* __restrict__ accb,           // [N][256] bf16 res
    u16* __restrict__ outb) {               // [N][256] bf16
  int n = (blockIdx.x * 256 + threadIdx.x) >> 6;
  if (n >= kN) return;
  int l = threadIdx.x & 63;
  int h = l >> 3, s = l & 7;
  int s0 = row_start[n], s1 = s0 + counts[n];
  float ern = er[n * 8 + h];
  float et0 = eterm[0 * 8 + h], et1 = eterm[1 * 8 + h], et2 = eterm[2 * 8 + h];
  float et3 = eterm[3 * 8 + h], et4 = eterm[4 * 8 + h];
  float m = -1e30f, ssum = 0.f;
  for (int i = s0 + s; i < s1; i += 8) {
    int e = edge_ids[i];
    int efc = ef[e];
    float etv = (efc == 0) ? et0 : (efc == 1) ? et1 : (efc == 2) ? et2 : (efc == 3) ? et3 : et4;
    float lg = el[src[e] * 8 + h] + ern + etv;
    lg = (lg < 0.f) ? 0.2f * lg : lg;
    if (lg > m) { ssum = ssum * expf(m - lg) + 1.f; m = lg; }
    else        { ssum += expf(lg - m); }
  }
  #pragma unroll
  for (int mk = 1; mk <= 4; mk <<= 1) {
    float om = __shfl_xor(m, mk);
    float os = __shfl_xor(ssum, mk);
    float nm = fmaxf(m, om);
    ssum = ssum * expf(m - nm) + os * expf(om - nm);
    m = nm;
  }
  float inv = 1.f / ssum;
  const size_t rowoff = (size_t)n * 256 + h * 32 + s * 4;
  ushort4 rv = *(const ushort4*)(accb + rowoff);
  float4 acc = make_float4(bf2f(rv.x), bf2f(rv.y), bf2f(rv.z), bf2f(rv.w));
  int i = s0;
  for (; i + 8 <= s1; i += 8) {
    int e = edge_ids[i + s];
    int sek = src[e];
    int efc = ef[e];
    float etv = (efc == 0) ? et0 : (efc == 1) ? et1 : (efc == 2) ? et2 : (efc == 3) ? et3 : et4;
    float lg = el[sek * 8 + h] + ern + etv;
    lg = (lg < 0.f) ? 0.2f * lg : lg;
    float am = expf(lg - m) * inv;
    am = am * (1.f - kAlpha) + (float)a0h[(size_t)e * 8 + h] * kAlpha;
    #pragma unroll
    for (int j = 0; j < 8; ++j) {
      float aj = __shfl(am, (h << 3) + j);
      int sej = __shfl(sek, j);
      ushort4 fv = *(const ushort4*)(featb + (size_t)sej * 256 + h * 32 + s * 4);
      acc.x = fmaf(aj, bf2f(fv.x), acc.x);
      acc.y = fmaf(aj, bf2f(fv.y), acc.y);
      acc.z = fmaf(aj, bf2f(fv.z), acc.z);
      acc.w = fmaf(aj, bf2f(fv.w), acc.w);
    }
  }
  if (i < s1) {
    int cnt = s1 - i;
    float am = 0.f; int sek = 0;
    if (s < cnt) {
      int e = edge_ids[i + s];
      sek = src[e];
      int efc = ef[e];
      float etv = (efc == 0) ? et0 : (efc == 1) ? et1 : (efc == 2) ? et2 : (efc == 3) ? et3 : et4;
      float lg = el[sek * 8 + h] + ern + etv;
      lg = (lg < 0.f) ? 0.2f * lg : lg;
      am = expf(lg - m) * inv;
      am = am * (1.f - kAlpha) + (float)a0h[(size_t)e * 8 + h] * kAlpha;
    }
    for (int j = 0; j < cnt; ++j) {
      float aj = __shfl(am, (h << 3) + j);
      int sej = __shfl(sek, j);
      ushort4 fv = *(const ushort4*)(featb + (size_t)sej * 256 + h * 32 + s * 4);
      acc.x = fmaf(aj, bf2f(fv.x), acc.x);
      acc.y = fmaf(aj, bf2f(fv.y), acc.y);
      acc.z = fmaf(aj, bf2f(fv.z), acc.z);
      acc.w = fmaf(aj, bf2f(fv.w), acc.w);
    }
  }
  acc.x = (acc.x > 0.f) ? acc.x : expm1f(acc.x);
  acc.y = (acc.y > 0.f) ? acc.y : expm1f(acc.y);
  acc.z = (acc.z > 0.f) ? acc.z : expm1f(acc.z);
  acc.w = (acc.w > 0.f) ? acc.w : expm1f(acc.w);
  ushort4 pw;
  pw.x = f2bf(acc.x); pw.y = f2bf(acc.y); pw.z = f2bf(acc.z); pw.w = f2bf(acc.w);
  *(ushort4*)(outb + rowoff) = pw;
}

// ============================================================
// Fused L2 aggregation + final head: 32 lanes per node.
// ============================================================
__global__ void __launch_bounds__(256) aggw1_final_kernel(
    const int* __restrict__ row_start, const int* __restrict__ counts,
    const int* __restrict__ edge_ids,
    const int* __restrict__ src, const int* __restrict__ ef,
    const float* __restrict__ el, const float* __restrict__ er,
    const float* __restrict__ eterm,        // [NE]
    const u16* __restrict__ featb,          // [N][32]
    const float* __restrict__ S2,           // [N][32]
    const float* __restrict__ ntf, const int* __restrict__ node_type,
    const float* __restrict__ dadelta,
    const float* __restrict__ finalW, const float* __restrict__ logitsW,
    float* __restrict__ out) {
  __shared__ float fWs[2048];
  __shared__ float lWs[512];
  __shared__ float abuf[8][32];
  __shared__ float bbuf[8][32];
  __shared__ float sbuf[8][32];
  const int tid = threadIdx.x;
  for (int i = tid; i < 2048; i += 256) fWs[i] = finalW[i];
  for (int i = tid; i < 512; i += 256) lWs[i] = logitsW[i];
  const int slot = tid >> 5;
  const int g = tid & 31;
  const int gb = tid & 32;
  const int n = blockIdx.x * 8 + slot;
  const int s0 = row_start[n], s1 = s0 + counts[n];
  float ern = er[n];
  float et0 = eterm[0], et1 = eterm[1], et2 = eterm[2], et3 = eterm[3], et4 = eterm[4];
  float m = -1e30f, ssum = 0.f;
  for (int i = s0 + g; i < s1; i += 32) {
    int e = edge_ids[i];
    int efc = ef[e];
    float etv = (efc == 0) ? et0 : (efc == 1) ? et1 : (efc == 2) ? et2 : (efc == 3) ? et3 : et4;
    float lg = el[src[e]] + ern + etv;
    lg = (lg < 0.f) ? 0.2f * lg : lg;
    if (lg > m) { ssum = ssum * expf(m - lg) + 1.f; m = lg; }
    else        { ssum += expf(lg - m); }
  }
  #pragma unroll
  for (int mk = 1; mk <= 16; mk <<= 1) {
    float om = __shfl_xor(m, mk);
    float os = __shfl_xor(ssum, mk);
    float nm = fmaxf(m, om);
    ssum = ssum * expf(m - nm) + os * expf(om - nm);
    m = nm;
  }
  float inv = 1.f / ssum;
  float acc = S2[(size_t)n * 32 + g];
  int i = s0;
  for (; i + 32 <= s1; i += 32) {
    int e = edge_ids[i + g];
    int sek = src[e];
    int efc = ef[e];
    float etv = (efc == 0) ? et0 : (efc == 1) ? et1 : (efc == 2) ? et2 : (efc == 3) ? et3 : et4;
    float lg = el[sek] + ern + etv;
    lg = (lg < 0.f) ? 0.2f * lg : lg;
    float am = expf(lg - m) * inv;
    #pragma unroll
    for (int j = 0; j < 32; ++j) {
      float aj = __shfl(am, gb + j);
      int sej = __shfl(sek, gb + j);
      acc = fmaf(aj, bf2f(featb[(size_t)sej * 32 + g]), acc);
    }
  }
  if (i < s1) {
    int cnt = s1 - i;
    float am = 0.f; int sek = 0;
    if (g < cnt) {
      int e = edge_ids[i + g];
      sek = src[e];
      int efc = ef[e];
      float etv = (efc == 0) ? et0 : (efc == 1) ? et1 : (efc == 2) ? et2 : (efc == 3) ? et3 : et4;
      float lg = el[sek] + ern + etv;
      lg = (lg < 0.f) ? 0.2f * lg : lg;
      am = expf(lg - m) * inv;
    }
    for (int j = 0; j < cnt; ++j) {
      float aj = __shfl(am, gb + j);
      int sej = __shfl(sek, gb + j);
      acc = fmaf(aj, bf2f(featb[(size_t)sej * 32 + g]), acc);
    }
  }
  float delta = dadelta[0];
  float ntv = ntf[node_type[n] * 32 + g];
  float av = acc;
  float bv = acc * ntv + delta;
  float na = av * av, nb = bv * bv;
  #pragma unroll
  for (int mk = 1; mk <= 16; mk <<= 1) {
    na += __shfl_xor(na, mk);
    nb += __shfl_xor(nb, mk);
  }
  float inva = 1.f / fmaxf(sqrtf(na), 1e-12f);
  float invb = 1.f / fmaxf(sqrtf(nb), 1e-12f);
  __syncthreads();
  abuf[slot][g] = av * inva;
  bbuf[slot][g] = bv * invb;
  __syncthreads();
  float s = 0.f;
  #pragma unroll
  for (int d = 0; d < 32; ++d)
    s += abuf[slot][d] * fWs[d * 32 + g] + bbuf[slot][d] * fWs[(32 + d) * 32 + g];
  s = fmaxf(s, 0.f);
  sbuf[slot][g] = s;
  __syncthreads();
  if (g < 16) {
    float lg = 0.f;
    #pragma unroll
    for (int o = 0; o < 32; ++o) lg += sbuf[slot][o] * lWs[o * 16 + g];
    float nl = lg * lg;
    #pragma unroll
    for (int mk = 1; mk <= 8; mk <<= 1) nl += __shfl_xor(nl, mk);
    float invl = 1.f / fmaxf(sqrtf(nl), 1e-12f);
    out[(size_t)n * 16 + g] = lg * invl;
  }
}

// ============================================================
extern "C" void kernel_launch(void* const* d_in, const int* in_sizes, int n_in,
                              void* d_out, int out_size, void* d_ws, size_t ws_size,
                              hipStream_t stream) {
  const float* feats     = (const float*)d_in[0];
  const int*   e_feat    = (const int*)d_in[1];
  const int*   node_type = (const int*)d_in[2];
  const int*   src       = (const int*)d_in[3];
  const int*   dst       = (const int*)d_in[4];
  const float* fc_W      = (const float*)d_in[5];
  const float* fc_b      = (const float*)d_in[6];
  const float* ntype_emb = (const float*)d_in[7];
  const float* W_ntype   = (const float*)d_in[8];
  const float* ta_edge_emb[3] = {(const float*)d_in[9],  (const float*)d_in[16], (const float*)d_in[24]};
  const float* ta_W[3]        = {(const float*)d_in[10], (const float*)d_in[17], (const float*)d_in[25]};
  const float* ta_We[3]       = {(const float*)d_in[11], (const float*)d_in[18], (const float*)d_in[26]};
  const float* ta_al[3]       = {(const float*)d_in[12], (const float*)d_in[19], (const float*)d_in[27]};
  const float* ta_ar[3]       = {(const float*)d_in[13], (const float*)d_in[20], (const float*)d_in[28]};
  const float* ta_ae[3]       = {(const float*)d_in[14], (const float*)d_in[21], (const float*)d_in[29]};
  const float* ta_bias[3]     = {(const float*)d_in[15], (const float*)d_in[22], (const float*)d_in[30]};
  const float* ta1_res_W = (const float*)d_in[23];
  const float* ta2_res_W = (const float*)d_in[31];
  const float* da_ln1_b  = (const float*)d_in[33];
  const float* da_Wv     = (const float*)d_in[38];
  const float* da_bv     = (const float*)d_in[39];
  const float* da_Wo     = (const float*)d_in[40];
  const float* da_bo     = (const float*)d_in[41];
  const float* da_ln2_b  = (const float*)d_in[43];
  const float* da_W1     = (const float*)d_in[44];
  const float* da_b1     = (const float*)d_in[45];
  const float* da_W2     = (const float*)d_in[46];
  const float* da_b2     = (const float*)d_in[47];
  const float* final_W   = (const float*)d_in[48];
  const float* logits_W  = (const float*)d_in[49];
  float* out = (float*)d_out;

  // ---- workspace layout (~51.3 MB, proven safe) ----
  char* base = (char*)d_ws;
  int* iws       = (int*)base;
  int* counts    = iws;                       // kN
  int* cursor    = iws + kN;                  // kN
  int* gcur      = iws + 2 * kN;              // 4 (padded)
  int* row_start = iws + 2 * kN + 4;          // kN
  int* edge_ids  = iws + 3 * kN + 4;          // kE
  char* p = base + (size_t)456004 * 4;
  float* ntf = (float*)p;                     p += 512;
  float* etm = (float*)p;                     p += 512;
  float* dad = (float*)p;                     p += 64;
  float* el  = (float*)p;                     p += (size_t)kN * 8 * 4;
  float* er  = (float*)p;                     p += (size_t)kN * 8 * 4;
  float* S2  = (float*)p;                     p += (size_t)kN * 32 * 4;
  u16*   Hb  = (u16*)p;                       p += (size_t)kN * 32 * 2;
  _Float16* a0h = (_Float16*)p;               p += (size_t)kE * 8 * 2;   // [E][8]
  u16* featb = (u16*)p;                       p += (size_t)kN * 256 * 2; // Gb / feat1 / feat2
  u16* Rb0   = (u16*)p;                       p += (size_t)kN * 256 * 2;
  u16* Rpr   = (u16*)p;                       p += (size_t)kN * 256 * 2;
  u16* WT0   = (u16*)p;                       p += (size_t)320 * 32 * 2;  // WT0el(2048) + Wbd0T(8192)
  u16* WT1   = (u16*)p;                       p += (size_t)576 * 256 * 2;
  u16* WT2   = (u16*)p;                       p += (size_t)128 * 256 * 2;
  u16* WT0el = WT0;
  u16* Wbd0T = WT0 + 2048;

  // --- CSR build (no serial scan) ---
  zero_ints_kernel<<<(2 * kN + 4 + 255) / 256, 256, 0, stream>>>(counts, 2 * kN + 4);
  count_kernel<<<kE / 256, 256, 0, stream>>>(dst, counts);
  alloc_kernel<<<(kN + 255) / 256, 256, 0, stream>>>(counts, gcur, row_start);
  scatter_kernel<<<kE / 256, 256, 0, stream>>>(dst, row_start, cursor, edge_ids);

  // --- merged precompute + pack ---
  prepack_kernel<<<745, 256, 0, stream>>>(
      ta_W[0], ta_al[0], ta_ar[0],
      ta_W[1], ta_al[1], ta_ar[1], ta1_res_W,
      ta_W[2], ta_al[2], ta_ar[2], ta2_res_W,
      WT0, WT1, WT2,
      ntype_emb, W_ntype,
      ta_edge_emb[0], ta_We[0], ta_ae[0],
      ta_edge_emb[1], ta_We[1], ta_ae[1],
      ta_edge_emb[2], ta_We[2], ta_ae[2],
      da_ln1_b, da_Wv, da_bv, da_Wo, da_bo,
      da_ln2_b, da_W1, da_b1, da_W2, da_b2,
      ntf, etm, dad);

  // --- input projection -> Hb bf16 ---
  inproj_kernel<<<(kN * 32) / 256, 256, 0, stream>>>(feats, fc_W, fc_b, ntf, node_type, Hb);

  // --- TA layer 0: el/er GEMM; h-space agg -> Gb; per-head GEMM -> Rb0 ---
  mfma_gemm_kernel<32><<<dim3(1, kN / 64), 256, 0, stream>>>(
      Hb, WT0el, nullptr, nullptr, el, er, nullptr, nullptr, 1, 0, 8, 0);
  agg8h_kernel<<<kN / 4, 256, 0, stream>>>(
      row_start, counts, edge_ids, src, e_feat, el, er, etm, Hb, a0h, featb);
  bd_gemm_kernel<<<kN / 64, 256, 0, stream>>>(featb, Wbd0T, ta_bias[0], Rb0);

  // --- TA layer 1: fused GEMM (3 tiles/block, 1125 blocks) then wave agg ---
  mfma_gemm_kernel<256><<<dim3(3, kN / 64), 256, 0, stream>>>(
      Rb0, WT1, ta_bias[1], featb, el, er, Rpr, nullptr, 3, 256, 8, 256);
  agg8w_kernel<<<kN / 4, 256, 0, stream>>>(
      row_start, counts, edge_ids, src, e_feat, el, er, etm + 40,
      featb, a0h, Rpr, Rpr);

  // --- TA layer 2: fused GEMM then fused 32-lane agg + final head ---
  mfma_gemm_kernel<256><<<dim3(2, kN / 64), 256, 0, stream>>>(
      Rpr, WT2, ta_bias[2], featb, el, er, nullptr, S2, 1, 32, 1, 32);
  aggw1_final_kernel<<<kN / 8, 256, 0, stream>>>(
      row_start, counts, edge_ids, src, e_feat, el, er, etm + 80, featb, S2,
      ntf, node_type, dad, final_W, logits_W, out);
}